// Round 10
// baseline (766.339 us; speedup 1.0000x reference)
//
#include <hip/hip_runtime.h>

#define NN 50000
#define NE 600000
#define DIM 128
#define NB_N 196   // ceil(50000/256)
#define NB_E 2344  // ceil(600000/256)
#define TILES 3125 // 50000/16
#define NEPAD (NE + 8 * NN + 64)  // rows padded to multiple of 8, min 8
#define SLOTN 25000               // dst nodes per half
#define CHUNK32 782               // ceil(25000/32) chunks per slot
#define SLAB ((size_t)(NN + 1) * 32)  // u16 per feature-slice blob (+sentinel)

typedef unsigned short u16;
typedef unsigned int u32;
typedef __attribute__((ext_vector_type(8))) short bf16x8;
typedef __attribute__((ext_vector_type(4))) float f32x4;

__device__ __forceinline__ u16 f2bf(float f) {
    u32 u = __builtin_bit_cast(u32, f);
    u32 r = (u + 0x7FFFu + ((u >> 16) & 1u)) >> 16;
    return (u16)r;
}
__device__ __forceinline__ float bflo(u32 w) { return __builtin_bit_cast(float, w << 16); }
__device__ __forceinline__ float bfhi(u32 w) { return __builtin_bit_cast(float, w & 0xffff0000u); }
__device__ __forceinline__ int pad8(int d) {
    int p = (d + 7) & ~7;
    return p < 8 ? 8 : p;
}

// ---- CSR build -------------------------------------------------------------

__global__ __launch_bounds__(256) void k_count(const int* __restrict__ ei,
                                               int* __restrict__ deg) {
    __shared__ int s64;
    if (threadIdx.x == 0) {
        int o = 0;
#pragma unroll
        for (int j = 0; j < 16; j++) o |= ei[2 * j + 1];  // int64 => high words 0
        s64 = (o == 0);
    }
    __syncthreads();
    int e = blockIdx.x * 256 + threadIdx.x;
    if (e >= NE) return;
    int d = s64 ? ei[2 * (NE + e)] : ei[NE + e];
    atomicAdd(&deg[d], 1);
}

__global__ __launch_bounds__(256) void k_scanA(const int* __restrict__ deg,
                                               int* __restrict__ rp8,
                                               int* __restrict__ bsum) {
    __shared__ int buf[256];
    int t = threadIdx.x, i = blockIdx.x * 256 + t;
    int v = (i < NN) ? pad8(deg[i]) : 0;
    buf[t] = v;
    __syncthreads();
    for (int off = 1; off < 256; off <<= 1) {
        int x = (t >= off) ? buf[t - off] : 0;
        __syncthreads();
        buf[t] += x;
        __syncthreads();
    }
    if (i < NN) rp8[i] = buf[t] - v;
    if (t == 255) bsum[blockIdx.x] = buf[255];
}

__global__ __launch_bounds__(256) void k_scanB(int* __restrict__ bsum) {
    __shared__ int buf[256];
    int t = threadIdx.x;
    int v = (t < NB_N) ? bsum[t] : 0;
    buf[t] = v;
    __syncthreads();
    for (int off = 1; off < 256; off <<= 1) {
        int x = (t >= off) ? buf[t - off] : 0;
        __syncthreads();
        buf[t] += x;
        __syncthreads();
    }
    bsum[t] = buf[t] - v;
}

__global__ __launch_bounds__(256) void k_scanC(const int* __restrict__ deg,
                                               int* __restrict__ rp8,
                                               const int* __restrict__ bsum,
                                               float* __restrict__ dinv) {
    int i = blockIdx.x * 256 + threadIdx.x;
    if (i < NN) {
        rp8[i] += bsum[i >> 8];
        dinv[i] = rsqrtf((float)(deg[i] + 1));  // +1 self loop
    }
    if (i == 0) rp8[NN] = bsum[255];
}

// fill CSR (src only) + wcast + pad entries -> sentinel NN + zero sentinel rows
__global__ __launch_bounds__(256) void k_fill(const int* __restrict__ ei,
                                              const int* __restrict__ rp8,
                                              int* __restrict__ cursor,
                                              const int* __restrict__ deg,
                                              int* __restrict__ recs,
                                              const float* __restrict__ W0,
                                              const float* __restrict__ W1,
                                              const float* __restrict__ W2,
                                              u16* __restrict__ Wt,
                                              u16* __restrict__ hwA) {
    __shared__ int s64;
    if (threadIdx.x == 0) {
        int o = 0;
#pragma unroll
        for (int j = 0; j < 16; j++) o |= ei[2 * j + 1];
        s64 = (o == 0);
    }
    __syncthreads();
    int e = blockIdx.x * 256 + threadIdx.x;
    if (e < NE) {
        int is64 = s64;
        int s = is64 ? ei[2 * e] : ei[e];
        int d = is64 ? ei[2 * (NE + e)] : ei[NE + e];
        int pos = rp8[d] + atomicAdd(&cursor[d], 1);
        recs[pos] = s;
    }
    int b = blockIdx.x;
    if (b < 192) {  // Wt[layer][n][k] = bf16(W[layer][k][n])
        int idx = b * 256 + threadIdx.x;
        int l = idx >> 14, rem = idx & 16383;
        int n = rem >> 7, k = rem & 127;
        const float* W = (l == 0) ? W0 : ((l == 1) ? W1 : W2);
        Wt[idx] = f2bf(W[k * 128 + n]);
    } else if (b < 388) {
        int i = (b - 192) * 256 + threadIdx.x;
        if (i < NN) {
            int rp = rp8[i], d = deg[i], p = pad8(d);
            for (int j = d; j < p; j++) recs[rp + j] = NN;
        }
    } else if (b == 388) {  // zero sentinel row (64 B) of each of 4 blobs
        int t = threadIdx.x;
        if (t < 64)
            ((u32*)(hwA + (size_t)(t >> 4) * SLAB + (size_t)NN * 32))[t & 15] = 0;
    }
}

// ---- layer-1 GEMM: hwS[p][v][:] = dinv[v]*(bf16(x) @ W0), slice-major out --
__global__ __launch_bounds__(256) void k_gemm_f32(const float* __restrict__ x,
                                                  const u16* __restrict__ Wt,
                                                  const float* __restrict__ dinv,
                                                  u16* __restrict__ hwS) {
    int lane = threadIdx.x & 63;
    int tile = blockIdx.x * 4 + (threadIdx.x >> 6);
    if (tile >= TILES) return;
    int r = lane & 15, q = lane >> 4;

    bf16x8 Bf[8][4];
#pragma unroll
    for (int nt = 0; nt < 8; nt++)
#pragma unroll
        for (int kc = 0; kc < 4; kc++)
            Bf[nt][kc] = *(const bf16x8*)(Wt + ((nt * 16 + r) << 7) + kc * 32 + q * 8);

    long rowbase = (long)tile * 16;
    bf16x8 Af[4];
#pragma unroll
    for (int kc = 0; kc < 4; kc++) {
        const float4* p = (const float4*)(x + (rowbase + r) * 128 + kc * 32 + q * 8);
        float4 t0 = p[0], t1 = p[1];
        bf16x8 a;
        a[0] = (short)f2bf(t0.x); a[1] = (short)f2bf(t0.y);
        a[2] = (short)f2bf(t0.z); a[3] = (short)f2bf(t0.w);
        a[4] = (short)f2bf(t1.x); a[5] = (short)f2bf(t1.y);
        a[6] = (short)f2bf(t1.z); a[7] = (short)f2bf(t1.w);
        Af[kc] = a;
    }

    float dv[4];
#pragma unroll
    for (int i = 0; i < 4; i++) dv[i] = dinv[rowbase + q * 4 + i];

#pragma unroll
    for (int nt = 0; nt < 8; nt++) {
        f32x4 acc = {0.f, 0.f, 0.f, 0.f};
#pragma unroll
        for (int kc = 0; kc < 4; kc++)
            acc = __builtin_amdgcn_mfma_f32_16x16x32_bf16(Af[kc], Bf[nt][kc], acc, 0, 0, 0);
#pragma unroll
        for (int i = 0; i < 4; i++)
            hwS[(size_t)(nt >> 1) * SLAB + (rowbase + q * 4 + i) * 32 +
                (nt & 1) * 16 + r] = f2bf(dv[i] * acc[i]);
    }
}

// ---- GEMM slice-major in/out: hwS_out = dinv * (hS_in @ W) -----------------
__global__ __launch_bounds__(256) void k_gemm(const u16* __restrict__ hS,
                                              const u16* __restrict__ Wt,
                                              const float* __restrict__ dinv,
                                              u16* __restrict__ hwS) {
    int lane = threadIdx.x & 63;
    int tile = blockIdx.x * 4 + (threadIdx.x >> 6);
    if (tile >= TILES) return;
    int r = lane & 15, q = lane >> 4;

    bf16x8 Bf[8][4];
#pragma unroll
    for (int nt = 0; nt < 8; nt++)
#pragma unroll
        for (int kc = 0; kc < 4; kc++)
            Bf[nt][kc] = *(const bf16x8*)(Wt + ((nt * 16 + r) << 7) + kc * 32 + q * 8);

    long rowbase = (long)tile * 16;
    bf16x8 Af[4];
#pragma unroll
    for (int kc = 0; kc < 4; kc++)
        Af[kc] = *(const bf16x8*)(hS + (size_t)kc * SLAB + (rowbase + r) * 32 + q * 8);

    float dv[4];
#pragma unroll
    for (int i = 0; i < 4; i++) dv[i] = dinv[rowbase + q * 4 + i];

#pragma unroll
    for (int nt = 0; nt < 8; nt++) {
        f32x4 acc = {0.f, 0.f, 0.f, 0.f};
#pragma unroll
        for (int kc = 0; kc < 4; kc++)
            acc = __builtin_amdgcn_mfma_f32_16x16x32_bf16(Af[kc], Bf[nt][kc], acc, 0, 0, 0);
#pragma unroll
        for (int i = 0; i < 4; i++)
            hwS[(size_t)(nt >> 1) * SLAB + (rowbase + q * 4 + i) * 32 +
                (nt & 1) * 16 + r] = f2bf(dv[i] * acc[i]);
    }
}

// ---- XCD-affine aggregation over slice-major slabs -------------------------
// 8 work slots = (slice p = slot>>1) x (dst half = slot&1). A block reads its
// REAL XCD id (HW_REG_XCC_ID) and drains slot==xcc first (slab p resident in
// this XCD's L2: 3.2 MB dense), then steals. Wave = 4 nodes x 2 edge-slots x
// 8 feat-lanes (4 feats, 8 B each). Chunk = 32 nodes per atomic claim.
__global__ __launch_bounds__(256) void k_agg_x(const u16* __restrict__ hwS,
                                               const int* __restrict__ rp8,
                                               const int* __restrict__ recs,
                                               const float* __restrict__ dinv,
                                               const float* __restrict__ bias,
                                               int* __restrict__ ctr,
                                               u16* __restrict__ hS_out,
                                               float* __restrict__ f_out,
                                               int write_f32) {
    int xcc;
    asm("s_getreg_b32 %0, hwreg(HW_REG_XCC_ID)" : "=s"(xcc));
    xcc &= 7;
    int lane = threadIdx.x & 63;
    int c = lane >> 4, e = (lane >> 3) & 1, f = lane & 7;

    for (int s = 0; s < 8; s++) {
        int slot = (xcc + s) & 7;
        if (*(volatile int*)(ctr + slot * 16) >= CHUNK32) continue;  // cheap probe
        int pass = slot >> 1, half = slot & 1;
        const u16* slab = hwS + (size_t)pass * SLAB;
        const float4 bb = *(const float4*)(bias + pass * 32 + f * 4);
        while (true) {
            int chunk;
            if (lane == 0) chunk = atomicAdd(ctr + slot * 16, 1);
            chunk = __shfl(chunk, 0, 64);
            if (chunk >= CHUNK32) break;
#pragma unroll 1
            for (int gi = 0; gi < 8; gi++) {
                int vloc = chunk * 32 + gi * 4 + c;
                if (vloc >= SLOTN) continue;
                int v = half * SLOTN + vloc;
                int start = rp8[v], end = rp8[v + 1];
                uint2 sv = *(const uint2*)(slab + (size_t)v * 32 + f * 4);
                float m = (e == 0) ? 1.0f : 0.0f;  // self term counted once
                float a0 = m * bflo(sv.x), a1 = m * bfhi(sv.x);
                float a2 = m * bflo(sv.y), a3 = m * bfhi(sv.y);
                for (int ee = start + e; ee < end; ee += 2) {
                    int src = __builtin_nontemporal_load(recs + ee);
                    uint2 u = *(const uint2*)(slab + (size_t)(u32)src * 32 + f * 4);
                    a0 += bflo(u.x); a1 += bfhi(u.x);
                    a2 += bflo(u.y); a3 += bfhi(u.y);
                }
                a0 += __shfl_xor(a0, 8, 64); a1 += __shfl_xor(a1, 8, 64);
                a2 += __shfl_xor(a2, 8, 64); a3 += __shfl_xor(a3, 8, 64);
                if (e == 0) {
                    float dv = dinv[v];
                    float r0 = fmaxf(fmaf(dv, a0, bb.x), 0.f);
                    float r1 = fmaxf(fmaf(dv, a1, bb.y), 0.f);
                    float r2 = fmaxf(fmaf(dv, a2, bb.z), 0.f);
                    float r3 = fmaxf(fmaf(dv, a3, bb.w), 0.f);
                    if (write_f32) {
                        *(float4*)(f_out + (size_t)v * DIM + pass * 32 + f * 4) =
                            make_float4(r0, r1, r2, r3);
                    } else {
                        uint2 pk;
                        pk.x = (u32)f2bf(r0) | ((u32)f2bf(r1) << 16);
                        pk.y = (u32)f2bf(r2) | ((u32)f2bf(r3) << 16);
                        *(uint2*)(hS_out + (size_t)pass * SLAB + (size_t)v * 32 +
                                  f * 4) = pk;
                    }
                }
            }
        }
    }
}

// ---- launch ----------------------------------------------------------------

extern "C" void kernel_launch(void* const* d_in, const int* in_sizes, int n_in,
                              void* d_out, int out_size, void* d_ws, size_t ws_size,
                              hipStream_t stream) {
    const float* x = (const float*)d_in[0];
    const int* ei = (const int*)d_in[1];
    const float* W0 = (const float*)d_in[2];
    const float* b0 = (const float*)d_in[3];
    const float* W1 = (const float*)d_in[4];
    const float* b1 = (const float*)d_in[5];
    const float* W2 = (const float*)d_in[6];
    const float* b2 = (const float*)d_in[7];

    char* ws = (char*)d_ws;
    size_t off = 0;
    auto alloc = [&](size_t bytes) -> void* {
        void* p = ws + off;
        off += (bytes + 511) & ~(size_t)511;
        return p;
    };
    int* deg = (int*)alloc(NN * 4);      // zeroed
    int* cursor = (int*)alloc(NN * 4);   // zeroed
    int* ctrA = (int*)alloc(128 * 4);    // zeroed (8 slots x 64 B stride)
    int* ctrB = (int*)alloc(128 * 4);    // zeroed
    int* ctrC = (int*)alloc(128 * 4);    // zeroed
    size_t zbytes = off;
    int* recs = (int*)alloc((size_t)NEPAD * 4);
    float* dinv = (float*)alloc(NN * 4);
    int* rp8 = (int*)alloc((NN + 1) * 4);
    int* bsum = (int*)alloc(256 * 4);
    u16* Wt = (u16*)alloc(3 * 128 * 128 * 2);
    u16* hwA = (u16*)alloc(4 * SLAB * 2);  // gathered slabs (sentinel zeroed)
    u16* hB = (u16*)alloc(4 * SLAB * 2);   // agg output slabs

    hipMemsetAsync(ws, 0, zbytes, stream);
    k_count<<<NB_E, 256, 0, stream>>>(ei, deg);
    k_scanA<<<NB_N, 256, 0, stream>>>(deg, rp8, bsum);
    k_scanB<<<1, 256, 0, stream>>>(bsum);
    k_scanC<<<NB_N, 256, 0, stream>>>(deg, rp8, bsum, dinv);
    k_fill<<<NB_E, 256, 0, stream>>>(ei, rp8, cursor, deg, recs,
                                     W0, W1, W2, Wt, hwA);
    k_gemm_f32<<<(TILES + 3) / 4, 256, 0, stream>>>(x, Wt, dinv, hwA);
    k_agg_x<<<1024, 256, 0, stream>>>(hwA, rp8, recs, dinv, b0, ctrA,
                                      hB, nullptr, 0);
    k_gemm<<<(TILES + 3) / 4, 256, 0, stream>>>(hB, Wt + 16384, dinv, hwA);
    k_agg_x<<<1024, 256, 0, stream>>>(hwA, rp8, recs, dinv, b1, ctrB,
                                      hB, nullptr, 0);
    k_gemm<<<(TILES + 3) / 4, 256, 0, stream>>>(hB, Wt + 32768, dinv, hwA);
    k_agg_x<<<1024, 256, 0, stream>>>(hwA, rp8, recs, dinv, b2, ctrC,
                                      nullptr, (float*)d_out, 1);
}

// Round 11
// 348.690 us; speedup vs baseline: 2.1978x; 2.1978x over previous
//
#include <hip/hip_runtime.h>

#define NN 50000
#define NE 600000
#define DIM 128
#define NB_N 196   // ceil(50000/256)
#define NB_E 2344  // ceil(600000/256)
#define TILES 3125 // 50000/16
#define NEPAD (NE + 4 * NN + 64)  // rows padded to multiple of 4, min 4
#define SLOTN 25000               // dst nodes per half
#define JBLK 1563                 // ceil(25000/16) blocks per slot
#define SLAB ((size_t)(NN + 1) * 32)  // u16 per feature-slice blob (+sentinel)

typedef unsigned short u16;
typedef unsigned int u32;
typedef __attribute__((ext_vector_type(8))) short bf16x8;
typedef __attribute__((ext_vector_type(4))) float f32x4;

__device__ __forceinline__ u16 f2bf(float f) {
    u32 u = __builtin_bit_cast(u32, f);
    u32 r = (u + 0x7FFFu + ((u >> 16) & 1u)) >> 16;
    return (u16)r;
}
__device__ __forceinline__ float bflo(u32 w) { return __builtin_bit_cast(float, w << 16); }
__device__ __forceinline__ float bfhi(u32 w) { return __builtin_bit_cast(float, w & 0xffff0000u); }
__device__ __forceinline__ int pad4(int d) {
    int p = (d + 3) & ~3;
    return p < 4 ? 4 : p;
}

// ---- CSR build -------------------------------------------------------------

__global__ __launch_bounds__(256) void k_count(const int* __restrict__ ei,
                                               int* __restrict__ deg) {
    __shared__ int s64;
    if (threadIdx.x == 0) {
        int o = 0;
#pragma unroll
        for (int j = 0; j < 16; j++) o |= ei[2 * j + 1];  // int64 => high words 0
        s64 = (o == 0);
    }
    __syncthreads();
    int e = blockIdx.x * 256 + threadIdx.x;
    if (e >= NE) return;
    int d = s64 ? ei[2 * (NE + e)] : ei[NE + e];
    atomicAdd(&deg[d], 1);
}

__global__ __launch_bounds__(256) void k_scanA(const int* __restrict__ deg,
                                               int* __restrict__ rp4,
                                               int* __restrict__ bsum) {
    __shared__ int buf[256];
    int t = threadIdx.x, i = blockIdx.x * 256 + t;
    int v = (i < NN) ? pad4(deg[i]) : 0;
    buf[t] = v;
    __syncthreads();
    for (int off = 1; off < 256; off <<= 1) {
        int x = (t >= off) ? buf[t - off] : 0;
        __syncthreads();
        buf[t] += x;
        __syncthreads();
    }
    if (i < NN) rp4[i] = buf[t] - v;
    if (t == 255) bsum[blockIdx.x] = buf[255];
}

__global__ __launch_bounds__(256) void k_scanB(int* __restrict__ bsum) {
    __shared__ int buf[256];
    int t = threadIdx.x;
    int v = (t < NB_N) ? bsum[t] : 0;
    buf[t] = v;
    __syncthreads();
    for (int off = 1; off < 256; off <<= 1) {
        int x = (t >= off) ? buf[t - off] : 0;
        __syncthreads();
        buf[t] += x;
        __syncthreads();
    }
    bsum[t] = buf[t] - v;
}

__global__ __launch_bounds__(256) void k_scanC(const int* __restrict__ deg,
                                               int* __restrict__ rp4,
                                               const int* __restrict__ bsum,
                                               float* __restrict__ dinv) {
    int i = blockIdx.x * 256 + threadIdx.x;
    if (i < NN) {
        rp4[i] += bsum[i >> 8];
        dinv[i] = rsqrtf((float)(deg[i] + 1));  // +1 self loop
    }
    if (i == 0) rp4[NN] = bsum[255];
}

// fill CSR (src only) + wcast + pad entries -> sentinel NN + zero sentinel rows
__global__ __launch_bounds__(256) void k_fill(const int* __restrict__ ei,
                                              const int* __restrict__ rp4,
                                              int* __restrict__ cursor,
                                              const int* __restrict__ deg,
                                              int* __restrict__ recs,
                                              const float* __restrict__ W0,
                                              const float* __restrict__ W1,
                                              const float* __restrict__ W2,
                                              u16* __restrict__ Wt,
                                              u16* __restrict__ hwA) {
    __shared__ int s64;
    if (threadIdx.x == 0) {
        int o = 0;
#pragma unroll
        for (int j = 0; j < 16; j++) o |= ei[2 * j + 1];
        s64 = (o == 0);
    }
    __syncthreads();
    int e = blockIdx.x * 256 + threadIdx.x;
    if (e < NE) {
        int is64 = s64;
        int s = is64 ? ei[2 * e] : ei[e];
        int d = is64 ? ei[2 * (NE + e)] : ei[NE + e];
        int pos = rp4[d] + atomicAdd(&cursor[d], 1);
        recs[pos] = s;
    }
    int b = blockIdx.x;
    if (b < 192) {  // Wt[layer][n][k] = bf16(W[layer][k][n])
        int idx = b * 256 + threadIdx.x;
        int l = idx >> 14, rem = idx & 16383;
        int n = rem >> 7, k = rem & 127;
        const float* W = (l == 0) ? W0 : ((l == 1) ? W1 : W2);
        Wt[idx] = f2bf(W[k * 128 + n]);
    } else if (b < 388) {  // pad entries -> sentinel NN
        int i = (b - 192) * 256 + threadIdx.x;
        if (i < NN) {
            int rp = rp4[i], d = deg[i], p = pad4(d);
            for (int j = d; j < p; j++) recs[rp + j] = NN;
        }
    } else if (b == 388) {  // zero sentinel row (64 B) of each of 4 blobs
        int t = threadIdx.x;
        if (t < 64)
            ((u32*)(hwA + (size_t)(t >> 4) * SLAB + (size_t)NN * 32))[t & 15] = 0;
    }
}

// ---- layer-1 GEMM: hwS[p][v][:] = dinv[v]*(bf16(x) @ W0), slice-major out --
__global__ __launch_bounds__(256) void k_gemm_f32(const float* __restrict__ x,
                                                  const u16* __restrict__ Wt,
                                                  const float* __restrict__ dinv,
                                                  u16* __restrict__ hwS) {
    int lane = threadIdx.x & 63;
    int tile = blockIdx.x * 4 + (threadIdx.x >> 6);
    if (tile >= TILES) return;
    int r = lane & 15, q = lane >> 4;

    bf16x8 Bf[8][4];
#pragma unroll
    for (int nt = 0; nt < 8; nt++)
#pragma unroll
        for (int kc = 0; kc < 4; kc++)
            Bf[nt][kc] = *(const bf16x8*)(Wt + ((nt * 16 + r) << 7) + kc * 32 + q * 8);

    long rowbase = (long)tile * 16;
    bf16x8 Af[4];
#pragma unroll
    for (int kc = 0; kc < 4; kc++) {
        const float4* p = (const float4*)(x + (rowbase + r) * 128 + kc * 32 + q * 8);
        float4 t0 = p[0], t1 = p[1];
        bf16x8 a;
        a[0] = (short)f2bf(t0.x); a[1] = (short)f2bf(t0.y);
        a[2] = (short)f2bf(t0.z); a[3] = (short)f2bf(t0.w);
        a[4] = (short)f2bf(t1.x); a[5] = (short)f2bf(t1.y);
        a[6] = (short)f2bf(t1.z); a[7] = (short)f2bf(t1.w);
        Af[kc] = a;
    }

    float dv[4];
#pragma unroll
    for (int i = 0; i < 4; i++) dv[i] = dinv[rowbase + q * 4 + i];

#pragma unroll
    for (int nt = 0; nt < 8; nt++) {
        f32x4 acc = {0.f, 0.f, 0.f, 0.f};
#pragma unroll
        for (int kc = 0; kc < 4; kc++)
            acc = __builtin_amdgcn_mfma_f32_16x16x32_bf16(Af[kc], Bf[nt][kc], acc, 0, 0, 0);
#pragma unroll
        for (int i = 0; i < 4; i++)
            hwS[(size_t)(nt >> 1) * SLAB + (rowbase + q * 4 + i) * 32 +
                (nt & 1) * 16 + r] = f2bf(dv[i] * acc[i]);
    }
}

// ---- GEMM slice-major in/out: hwS_out = dinv * (hS_in @ W) -----------------
__global__ __launch_bounds__(256) void k_gemm(const u16* __restrict__ hS,
                                              const u16* __restrict__ Wt,
                                              const float* __restrict__ dinv,
                                              u16* __restrict__ hwS) {
    int lane = threadIdx.x & 63;
    int tile = blockIdx.x * 4 + (threadIdx.x >> 6);
    if (tile >= TILES) return;
    int r = lane & 15, q = lane >> 4;

    bf16x8 Bf[8][4];
#pragma unroll
    for (int nt = 0; nt < 8; nt++)
#pragma unroll
        for (int kc = 0; kc < 4; kc++)
            Bf[nt][kc] = *(const bf16x8*)(Wt + ((nt * 16 + r) << 7) + kc * 32 + q * 8);

    long rowbase = (long)tile * 16;
    bf16x8 Af[4];
#pragma unroll
    for (int kc = 0; kc < 4; kc++)
        Af[kc] = *(const bf16x8*)(hS + (size_t)kc * SLAB + (rowbase + r) * 32 + q * 8);

    float dv[4];
#pragma unroll
    for (int i = 0; i < 4; i++) dv[i] = dinv[rowbase + q * 4 + i];

#pragma unroll
    for (int nt = 0; nt < 8; nt++) {
        f32x4 acc = {0.f, 0.f, 0.f, 0.f};
#pragma unroll
        for (int kc = 0; kc < 4; kc++)
            acc = __builtin_amdgcn_mfma_f32_16x16x32_bf16(Af[kc], Bf[nt][kc], acc, 0, 0, 0);
#pragma unroll
        for (int i = 0; i < 4; i++)
            hwS[(size_t)(nt >> 1) * SLAB + (rowbase + q * 4 + i) * 32 +
                (nt & 1) * 16 + r] = f2bf(dv[i] * acc[i]);
    }
}

// ---- XCD-affine sliced aggregation, quad-chain high-ILP loop ---------------
// slot = blockIdx & 7 (round-robin -> XCD): slice p = slot>>1, dst half =
// slot&1. Slab p = 3.2 MB dense, fits the XCD's 4 MiB L2. Wave = 4 chains
// (nodes) x 4 edge-groups (g) x 16 feat-lanes (r: u32 = 2 feats). Per iter: 4
// gather instructions = 16 independent 64-B lines in flight, 16 edges consumed.
__global__ __launch_bounds__(256) void k_agg_q(const u16* __restrict__ hwS,
                                               const int* __restrict__ rp4,
                                               const int* __restrict__ recs,
                                               const float* __restrict__ dinv,
                                               const float* __restrict__ bias,
                                               u16* __restrict__ hS_out,
                                               float* __restrict__ f_out,
                                               int write_f32) {
    int b = blockIdx.x;
    int slot = b & 7, j = b >> 3;
    int pass = slot >> 1, half = slot & 1;
    int w = threadIdx.x >> 6;
    int vloc = j * 16 + w * 4;
    if (vloc >= SLOTN) return;
    int vbase = half * SLOTN + vloc;
    int lane = threadIdx.x & 63;
    int g = lane >> 4, r = lane & 15;
    const u16* slab = hwS + (size_t)pass * SLAB;

    int4 rlo = *(const int4*)(rp4 + vbase);  // vbase % 4 == 0
    int rhi = rp4[vbase + 4];
    int s0 = rlo.x, s1 = rlo.y, s2 = rlo.z, s3 = rlo.w;
    int l0 = rlo.y - rlo.x, l1 = rlo.z - rlo.y, l2 = rlo.w - rlo.z, l3 = rhi - rlo.w;

    // self rows: group g loads chain g's row; counted once (only c==g lanes)
    u32 sv = *(const u32*)(slab + (size_t)(vbase + g) * 32 + r * 2);
    float A[4][2];
#pragma unroll
    for (int c = 0; c < 4; c++) {
        float m = (g == c) ? 1.0f : 0.0f;
        A[c][0] = m * bflo(sv);
        A[c][1] = m * bfhi(sv);
    }

    int l_max = max(max(l0, l1), max(l2, l3));
    for (int cur = 0; cur < l_max; cur += 4) {
        int i0 = s0 + min(cur, l0 - 4) + g;  // clamped re-read past row end
        int i1 = s1 + min(cur, l1 - 4) + g;
        int i2 = s2 + min(cur, l2 - 4) + g;
        int i3 = s3 + min(cur, l3 - 4) + g;
        int e0 = __builtin_nontemporal_load(recs + i0);
        int e1 = __builtin_nontemporal_load(recs + i1);
        int e2 = __builtin_nontemporal_load(recs + i2);
        int e3 = __builtin_nontemporal_load(recs + i3);
        if (cur >= l0) e0 = NN;  // clamped re-reads -> sentinel (zeros)
        if (cur >= l1) e1 = NN;
        if (cur >= l2) e2 = NN;
        if (cur >= l3) e3 = NN;
        u32 u0 = *(const u32*)(slab + (size_t)(u32)e0 * 32 + r * 2);
        u32 u1 = *(const u32*)(slab + (size_t)(u32)e1 * 32 + r * 2);
        u32 u2 = *(const u32*)(slab + (size_t)(u32)e2 * 32 + r * 2);
        u32 u3 = *(const u32*)(slab + (size_t)(u32)e3 * 32 + r * 2);
        A[0][0] += bflo(u0); A[0][1] += bfhi(u0);
        A[1][0] += bflo(u1); A[1][1] += bfhi(u1);
        A[2][0] += bflo(u2); A[2][1] += bfhi(u2);
        A[3][0] += bflo(u3); A[3][1] += bfhi(u3);
    }

    // reduce over edge-groups (lane bits 4,5)
#pragma unroll
    for (int c = 0; c < 4; c++) {
        A[c][0] += __shfl_xor(A[c][0], 16, 64);
        A[c][1] += __shfl_xor(A[c][1], 16, 64);
        A[c][0] += __shfl_xor(A[c][0], 32, 64);
        A[c][1] += __shfl_xor(A[c][1], 32, 64);
    }

    // lane group g writes chain g (all 64 lanes write distinct addresses)
    float a0 = (g == 0) ? A[0][0] : (g == 1) ? A[1][0] : (g == 2) ? A[2][0] : A[3][0];
    float a1 = (g == 0) ? A[0][1] : (g == 1) ? A[1][1] : (g == 2) ? A[2][1] : A[3][1];
    float dv = dinv[vbase + g];
    float2 bb = *(const float2*)(bias + pass * 32 + r * 2);
    float r0 = fmaxf(fmaf(dv, a0, bb.x), 0.f);
    float r1 = fmaxf(fmaf(dv, a1, bb.y), 0.f);
    if (write_f32) {
        *(float2*)(f_out + (size_t)(vbase + g) * DIM + pass * 32 + r * 2) =
            make_float2(r0, r1);
    } else {
        u32 pk = (u32)f2bf(r0) | ((u32)f2bf(r1) << 16);
        *(u32*)(hS_out + (size_t)pass * SLAB + (size_t)(vbase + g) * 32 + r * 2) = pk;
    }
}

// ---- launch ----------------------------------------------------------------

extern "C" void kernel_launch(void* const* d_in, const int* in_sizes, int n_in,
                              void* d_out, int out_size, void* d_ws, size_t ws_size,
                              hipStream_t stream) {
    const float* x = (const float*)d_in[0];
    const int* ei = (const int*)d_in[1];
    const float* W0 = (const float*)d_in[2];
    const float* b0 = (const float*)d_in[3];
    const float* W1 = (const float*)d_in[4];
    const float* b1 = (const float*)d_in[5];
    const float* W2 = (const float*)d_in[6];
    const float* b2 = (const float*)d_in[7];

    char* ws = (char*)d_ws;
    size_t off = 0;
    auto alloc = [&](size_t bytes) -> void* {
        void* p = ws + off;
        off += (bytes + 511) & ~(size_t)511;
        return p;
    };
    int* deg = (int*)alloc(NN * 4);      // zeroed
    int* cursor = (int*)alloc(NN * 4);   // zeroed
    size_t zbytes = off;
    int* recs = (int*)alloc((size_t)NEPAD * 4);
    float* dinv = (float*)alloc(NN * 4);
    int* rp4 = (int*)alloc((NN + 1) * 4);
    int* bsum = (int*)alloc(256 * 4);
    u16* Wt = (u16*)alloc(3 * 128 * 128 * 2);
    u16* hwA = (u16*)alloc(4 * SLAB * 2);  // gathered slabs (sentinel zeroed)
    u16* hB = (u16*)alloc(4 * SLAB * 2);   // agg output slabs

    hipMemsetAsync(ws, 0, zbytes, stream);
    k_count<<<NB_E, 256, 0, stream>>>(ei, deg);
    k_scanA<<<NB_N, 256, 0, stream>>>(deg, rp4, bsum);
    k_scanB<<<1, 256, 0, stream>>>(bsum);
    k_scanC<<<NB_N, 256, 0, stream>>>(deg, rp4, bsum, dinv);
    k_fill<<<NB_E, 256, 0, stream>>>(ei, rp4, cursor, deg, recs,
                                     W0, W1, W2, Wt, hwA);
    k_gemm_f32<<<(TILES + 3) / 4, 256, 0, stream>>>(x, Wt, dinv, hwA);
    k_agg_q<<<8 * JBLK, 256, 0, stream>>>(hwA, rp4, recs, dinv, b0,
                                          hB, nullptr, 0);
    k_gemm<<<(TILES + 3) / 4, 256, 0, stream>>>(hB, Wt + 16384, dinv, hwA);
    k_agg_q<<<8 * JBLK, 256, 0, stream>>>(hwA, rp4, recs, dinv, b1,
                                          hB, nullptr, 0);
    k_gemm<<<(TILES + 3) / 4, 256, 0, stream>>>(hB, Wt + 32768, dinv, hwA);
    k_agg_q<<<8 * JBLK, 256, 0, stream>>>(hwA, rp4, recs, dinv, b2,
                                          nullptr, (float*)d_out, 1);
}